// Round 10
// baseline (160.973 us; speedup 1.0000x reference)
//
#include <hip/hip_runtime.h>

#define DIM 4096
using F2 = float2;

// R10: R9 structure (128 thr, 32 amps/thread, 5 phases, fused L0 ring) but the
// LDS transpose buffer is halved to 16 KB (2048 F2) by doing each transpose in
// two rounds split on an amplitude bit that is a reg bit in BOTH layouts
// (a[7] for A<->B, a[3] for B<->C). Destination slot numbering is permuted so
// round-h loads exactly the round-h stored amp[] slots (no clobber, no temps).
// => LDS 16 KB -> 8 blocks/CU resident (VGPR-capped) = whole 2048-block grid
// co-resident, no tail. Qubit q lives at amplitude bit (11-q).
//
// Layout A (canonical): amp = (s<<7)|t.  Qubit masks: q0..q4 = 16,8,4,2,1.
// Layout B (permuted):  r = {s0 -> r4, s[4:1] -> r[3:0]}; amp = (t[6:3]<<8)|(r<<3)|t[2:0].
//                       Masks: q4=1, q5=16, q6=8, q7=4, q8=2.  a[7]=s0, a[3]=s1.
// Layout C (permuted):  c = {u0->c0, u1->c4, u4->c3, u3->c2, u2->c1};
//                       amp = (c0<<11)|(t<<4)|(c4<<3)|(c3<<2)|(c2<<1)|c1.
//                       Masks: q8=2, q9=16, q10=8, q11=4, q0=1.  a[3]=u1.

__device__ __forceinline__ int swzb(int i) { return i ^ ((i >> 6) & 15); }  // 4-lane/bank-pair in all phases
__device__ __forceinline__ int ampA(int s, int t) { return (s << 7) | t; }
__device__ __forceinline__ int ampB(int s, int t) {
    int r = ((s >> 1) & 15) | ((s & 1) << 4);
    return ((t >> 3) << 8) | (r << 3) | (t & 7);
}
__device__ __forceinline__ int ampC(int u, int t) {
    return ((u & 1) << 11) | (t << 4) | (((u >> 1) & 1) << 3) |
           (((u >> 4) & 1) << 2) | (((u >> 3) & 1) << 1) | ((u >> 2) & 1);
}
__device__ __forceinline__ int bx7(int a) { return ((a >> 8) << 7) | (a & 127); }  // drop a[7]
__device__ __forceinline__ int bx3(int a) { return ((a >> 4) << 3) | (a & 7); }    // drop a[3]

// ---- packed fp32 complex primitives (VOP3P) — proven R8/R9 ----
__device__ __forceinline__ F2 pk_mul_bl(F2 a, F2 u) {   // (a.x*u.x, a.y*u.x)
    F2 d;
    asm("v_pk_mul_f32 %0, %1, %2 op_sel:[0,0] op_sel_hi:[1,0]"
        : "=v"(d) : "v"(a), "v"(u));
    return d;
}
__device__ __forceinline__ void pk_cross(F2& d, F2 a, F2 u) {  // d += (-a.y*u.y, a.x*u.y)
    asm("v_pk_fma_f32 %0, %1, %2, %0 op_sel:[1,1,0] op_sel_hi:[0,1,1] neg_lo:[1,0,0]"
        : "+v"(d) : "v"(a), "v"(u));
}
__device__ __forceinline__ void pk_fma_bl(F2& d, F2 a, F2 u) { // d += (a.x*u.x, a.y*u.x)
    asm("v_pk_fma_f32 %0, %1, %2, %0 op_sel:[0,0,0] op_sel_hi:[1,0,1]"
        : "+v"(d) : "v"(a), "v"(u));
}
__device__ __forceinline__ void pk_swapneg(F2& d, F2 a, F2 cs) { // d += (a.y*cs.y, -a.x*cs.y)
    asm("v_pk_fma_f32 %0, %1, %2, %0 op_sel:[1,1,0] op_sel_hi:[0,1,1] neg_hi:[1,0,0]"
        : "+v"(d) : "v"(a), "v"(cs));
}
__device__ __forceinline__ void pk_fma(F2& d, F2 a, F2 b) {    // d += a*b
    asm("v_pk_fma_f32 %0, %1, %2, %0" : "+v"(d) : "v"(a), "v"(b));
}
__device__ __forceinline__ void pk_imacc(F2& d, F2 a0, F2 a1) { // d += (a0.x*a1.y, -a0.y*a1.x)
    asm("v_pk_fma_f32 %0, %1, %2, %0 op_sel:[0,1,0] op_sel_hi:[1,0,1] neg_hi:[1,0,0]"
        : "+v"(d) : "v"(a0), "v"(a1));
}
__device__ __forceinline__ F2 pk_cmul(F2 u, F2 a) {
    F2 d = pk_mul_bl(a, u);
    pk_cross(d, a, u);
    return d;
}
__device__ __forceinline__ void pk_cfma(F2& d, F2 u, F2 a) {
    pk_fma_bl(d, a, u);
    pk_cross(d, a, u);
}

__device__ __forceinline__ void build_u(float tx, float ty, float tz, float* u) {
    float sx = sinf(0.5f*tx), cx = cosf(0.5f*tx);
    float sy = sinf(0.5f*ty), cy = cosf(0.5f*ty);
    float sz = sinf(0.5f*tz), cz = cosf(0.5f*tz);
    float A00r = cy*cx, A00i =  sy*sx;     // A = Ry*Rx
    float A01r = -sy*cx, A01i = -cy*sx;
    float A10r =  sy*cx, A10i = -cy*sx;
    float A11r =  cy*cx, A11i = -sy*sx;
    // U = Rz*A: row0 *= (cz - i sz), row1 *= (cz + i sz)   [verified r1/3/5..9]
    u[0] = cz*A00r + sz*A00i;  u[1] = cz*A00i - sz*A00r;
    u[2] = cz*A01r + sz*A01i;  u[3] = cz*A01i - sz*A01r;
    u[4] = cz*A10r - sz*A10i;  u[5] = cz*A10i + sz*A10r;
    u[6] = cz*A11r - sz*A11i;  u[7] = cz*A11i + sz*A11r;
}

// coef layout (floats): [0..95] U0 plain (q*8); [96..191] RX(ang[36+q-1])*U0[q] (q=1..11);
// [192..287] U1 plain; [288..295] U1[0]*RX(ang[47]); [296..319] L1 CRX (cos,sin)[c=0..11]
__global__ void prep_kernel(const float* __restrict__ ang, float* __restrict__ coef) {
    int t = threadIdx.x;
    if (t < 12) {
        float u[8]; build_u(ang[t], ang[12+t], ang[24+t], u);
#pragma unroll
        for (int j = 0; j < 8; ++j) coef[t*8 + j] = u[j];
    } else if (t < 24) {
        int q = t - 12;
        float u[8]; build_u(ang[48+q], ang[60+q], ang[72+q], u);
#pragma unroll
        for (int j = 0; j < 8; ++j) coef[192 + q*8 + j] = u[j];
    } else if (t < 36) {
        int c = t - 24;
        float th = 0.5f * ang[95 - c];     // L1 ring gate (c,c+1) = tape slot 84+(11-c)
        coef[296 + c*2]     = cosf(th);
        coef[296 + c*2 + 1] = sinf(th);
    } else if (t < 47) {
        int q = t - 35;                    // 1..11: M = RX(ang[36+q-1]) * U0[q]
        float u[8]; build_u(ang[q], ang[12+q], ang[24+q], u);
        float c = cosf(0.5f*ang[36+q-1]), s = sinf(0.5f*ang[36+q-1]);
        float m[8];
        m[0] = c*u[0] + s*u[5];  m[1] = c*u[1] - s*u[4];   // M00 = c u00 - i s u10
        m[2] = c*u[2] + s*u[7];  m[3] = c*u[3] - s*u[6];   // M01 = c u01 - i s u11
        m[4] = s*u[1] + c*u[4];  m[5] = -s*u[0] + c*u[5];  // M10 = -i s u00 + c u10
        m[6] = s*u[3] + c*u[6];  m[7] = -s*u[2] + c*u[7];  // M11 = -i s u01 + c u11
#pragma unroll
        for (int j = 0; j < 8; ++j) coef[96 + q*8 + j] = m[j];
    } else if (t == 47) {                  // M = U1[0] * RX(ang[47])  [CR0(11,0) then U1(0)]
        float u[8]; build_u(ang[48], ang[60], ang[72], u);
        float c = cosf(0.5f*ang[47]), s = sinf(0.5f*ang[47]);
        float m[8];
        m[0] = c*u[0] + s*u[3];  m[1] = c*u[1] - s*u[2];   // M00 = c u00 - i s u01
        m[2] = s*u[1] + c*u[2];  m[3] = -s*u[0] + c*u[3];  // M01 = -i s u00 + c u01
        m[4] = c*u[4] + s*u[7];  m[5] = c*u[5] - s*u[6];   // M10 = c u10 - i s u11
        m[6] = s*u[5] + c*u[6];  m[7] = -s*u[4] + c*u[7];  // M11 = -i s u10 + c u11
#pragma unroll
        for (int j = 0; j < 8; ++j) coef[288 + j] = m[j];
    }
}

template<int M>  // plain fused-1q on reg-bit M pairs (16 pairs over 32 slots)
__device__ __forceinline__ void g1q(F2* amp, const float* __restrict__ u) {
    F2 u00 = {u[0], u[1]}, u01 = {u[2], u[3]};
    F2 u10 = {u[4], u[5]}, u11 = {u[6], u[7]};
#pragma unroll
    for (int r0 = 0; r0 < 32; ++r0) {
        if (r0 & M) continue;
        const int r1 = r0 + M;
        F2 a0 = amp[r0], a1 = amp[r1];
        F2 n0 = pk_cmul(u00, a0); pk_cfma(n0, u01, a1);
        F2 n1 = pk_cmul(u10, a0); pk_cfma(n1, u11, a1);
        amp[r0] = n0; amp[r1] = n1;
    }
}

// 1q gate with matrix selected by compile-time control reg bit MSEL
template<int MSEL, int M>
__device__ __forceinline__ void fg1q(F2* amp, const float* __restrict__ uA,
                                     const float* __restrict__ uB) {
    F2 a00 = {uA[0], uA[1]}, a01 = {uA[2], uA[3]}, a10 = {uA[4], uA[5]}, a11 = {uA[6], uA[7]};
    F2 b00 = {uB[0], uB[1]}, b01 = {uB[2], uB[3]}, b10 = {uB[4], uB[5]}, b11 = {uB[6], uB[7]};
#pragma unroll
    for (int r0 = 0; r0 < 32; ++r0) {
        if (r0 & M) continue;
        const int r1 = r0 + M;
        const bool sel = (r0 & MSEL) != 0;           // compile-time
        F2 u00 = sel ? b00 : a00, u01 = sel ? b01 : a01;
        F2 u10 = sel ? b10 : a10, u11 = sel ? b11 : a11;
        F2 a0 = amp[r0], a1 = amp[r1];
        F2 n0 = pk_cmul(u00, a0); pk_cfma(n0, u01, a1);
        F2 n1 = pk_cmul(u10, a0); pk_cfma(n1, u11, a1);
        amp[r0] = n0; amp[r1] = n1;
    }
}

template<int MC, int MT>  // plain CRX (8 pairs over 32 slots)
__device__ __forceinline__ void crx(F2* amp, F2 cs) {
#pragma unroll
    for (int r0 = 0; r0 < 32; ++r0) {
        if (!(r0 & MC) || (r0 & MT)) continue;
        const int r1 = r0 + MT;
        F2 a0 = amp[r0], a1 = amp[r1];
        F2 n0 = pk_mul_bl(a0, cs); pk_swapneg(n0, a1, cs);
        F2 n1 = pk_mul_bl(a1, cs); pk_swapneg(n1, a0, cs);
        amp[r0] = n0; amp[r1] = n1;
    }
}

template<int M>  // wave-reduce <X_q>,<Y_q>,<Z_q>; park totals in lane q
__device__ __forceinline__ void expv(const F2* amp, int q, int lane,
                                     float& fx, float& fy, float& fz) {
    F2 zp = {0.f, 0.f}, zm = {0.f, 0.f}, xp = {0.f, 0.f}, ip = {0.f, 0.f};
#pragma unroll
    for (int r0 = 0; r0 < 32; ++r0) {
        if (r0 & M) continue;
        const int r1 = r0 + M;
        F2 a0 = amp[r0], a1 = amp[r1];
        pk_fma(zp, a0, a0);
        pk_fma(zm, a1, a1);
        pk_fma(xp, a0, a1);
        pk_imacc(ip, a0, a1);
    }
    float zz = (zp.x + zp.y) - (zm.x + zm.y);
    float xr = 2.f * (xp.x + xp.y);
    float xi = 2.f * (ip.x + ip.y);
#pragma unroll
    for (int off = 32; off; off >>= 1) {
        xr += __shfl_xor(xr, off);
        xi += __shfl_xor(xi, off);
        zz += __shfl_xor(zz, off);
    }
    if (lane == q) { fx = xr; fy = xi; fz = zz; }
}

// Two-round transpose: round h stores slots with (slot bit SB)==h via SRC addr,
// loads the SAME slot set via DST addr. Buffer = 2048 F2.
#define XP2(SB, SRC, BXS, DST, BXD) \
  { _Pragma("unroll") \
    for (int h = 0; h < 2; ++h) { \
      _Pragma("unroll") \
      for (int s = 0; s < 32; ++s) \
        if (((s >> SB) & 1) == h) buf[swzb(BXS(SRC(s, t)))] = amp[s]; \
      __syncthreads(); \
      _Pragma("unroll") \
      for (int s = 0; s < 32; ++s) \
        if (((s >> SB) & 1) == h) amp[s] = buf[swzb(BXD(DST(s, t)))]; \
      __syncthreads(); \
    } }

#define U0P(q, M)        g1q<M>(amp, cf + (q)*8)
#define FU0(q, MSEL, M)  fg1q<MSEL, M>(amp, cf + (q)*8, cf + 96 + (q)*8)
#define U1P(q, M)        g1q<M>(amp, cf + 192 + (q)*8)
#define CR1(c, MC, MT)   crx<MC, MT>(amp, F2{cf[296 + (c)*2], cf[296 + (c)*2 + 1]})
#define EXPV(q, M)       expv<M>(amp, q, lane, fx, fy, fz)

__global__ __launch_bounds__(128, 1)
void qsim_kernel(const float* __restrict__ sv,      // [B, 4096]
                 const float* __restrict__ cf,      // [320] precomputed coefficients
                 const float* __restrict__ W,       // [10, 36]
                 const float* __restrict__ bvec,    // [10]
                 float* __restrict__ out)           // [B, 10]
{
    __shared__ F2 buf[DIM / 2];      // 16 KB -> 8 blocks/CU (VGPR-capped), grid co-resident
    const int t = threadIdx.x;
    const int b = blockIdx.x;
    const int lane = t & 63, w = t >> 6;

    F2 amp[32];
    const float* svb = sv + (size_t)b * DIM;
#pragma unroll
    for (int r = 0; r < 32; ++r)                    // layout A, coalesced
        amp[r] = make_float2(svb[(r << 7) | t], 0.f);

    float fx = 0.f, fy = 0.f, fz = 0.f;

    // ---- A {q0..q4 = 16,8,4,2,1}: U0(0); [U0(q);CR0(q-1,q)] q=1..4 ----
    U0P(0, 16);
    FU0(1, 16, 8); FU0(2, 8, 4); FU0(3, 4, 2); FU0(4, 2, 1);
    XP2(0, ampA, bx7, ampB, bx7);                  // split a[7]: A s0 / B s0

    // ---- B {q4=1,q5=16,q6=8,q7=4,q8=2}: [U0(q);CR0(q-1,q)] q=5..8 ----
    FU0(5, 1, 16); FU0(6, 16, 8); FU0(7, 8, 4); FU0(8, 4, 2);
    XP2(1, ampB, bx3, ampC, bx3);                  // split a[3]: B s1 / C u1

    // ---- C {q8=2,q9=16,q10=8,q11=4,q0=1}: [U0(q);CR0(q-1,q)] q=9..11;
    //      [CR0(11,0);U1(0)]; U1(8..11); L1 ring (11,0),(10,11),(9,10),(8,9);
    //      expv 9,10,11 ----
    FU0(9, 2, 16); FU0(10, 16, 8); FU0(11, 8, 4);
    fg1q<4, 1>(amp, cf + 192, cf + 288);           // ctrl q11(4) -> U1(0) or U1(0)*RX
    U1P(8, 2); U1P(9, 16); U1P(10, 8); U1P(11, 4);
    CR1(11, 4, 1); CR1(10, 8, 4); CR1(9, 16, 8); CR1(8, 2, 16);
    EXPV(9, 16); EXPV(10, 8); EXPV(11, 4);
    XP2(1, ampC, bx3, ampB, bx3);                  // back: split a[3]

    // ---- B' : U1(4..7); L1 ring (7,8),(6,7),(5,6),(4,5); expv 5,6,7,8 ----
    U1P(4, 1); U1P(5, 16); U1P(6, 8); U1P(7, 4);
    CR1(7, 4, 2); CR1(6, 8, 4); CR1(5, 16, 8); CR1(4, 1, 16);
    EXPV(5, 16); EXPV(6, 8); EXPV(7, 4); EXPV(8, 2);
    XP2(0, ampB, bx7, ampA, bx7);                  // back: split a[7]

    // ---- A' : U1(1,2,3); L1 ring (3,4),(2,3),(1,2),(0,1); expv 0..4 ----
    U1P(1, 8); U1P(2, 4); U1P(3, 2);
    CR1(3, 2, 1); CR1(2, 4, 2); CR1(1, 8, 4); CR1(0, 16, 8);
    EXPV(0, 16); EXPV(1, 8); EXPV(2, 4); EXPV(3, 2); EXPV(4, 1);

    // ---- combine 2 waves' features (buf dead: alias), head, store ----
    float* fbuf = (float*)buf;       // [2][36]
    if (lane < 12) {
        fbuf[w * 36 + lane]      = fx;
        fbuf[w * 36 + 12 + lane] = fy;
        fbuf[w * 36 + 24 + lane] = fz;
    }
    __syncthreads();
    if (t < 10) {
        float a = bvec[t];
#pragma unroll
        for (int f = 0; f < 36; ++f)
            a += W[t * 36 + f] * (fbuf[f] + fbuf[36 + f]);
        out[(size_t)b * 10 + t] = a;
    }
}

extern "C" void kernel_launch(void* const* d_in, const int* in_sizes, int n_in,
                              void* d_out, int out_size, void* d_ws, size_t ws_size,
                              hipStream_t stream) {
    const float* sv     = (const float*)d_in[0];
    const float* angles = (const float*)d_in[1];
    const float* W      = (const float*)d_in[2];
    const float* bvec   = (const float*)d_in[3];
    float* out  = (float*)d_out;
    float* coef = (float*)d_ws;      // 320 floats of scratch
    int batch = in_sizes[0] / DIM;   // 2048
    prep_kernel<<<1, 64, 0, stream>>>(angles, coef);
    qsim_kernel<<<batch, 128, 0, stream>>>(sv, coef, W, bvec, out);
}